// Round 2
// baseline (2902.421 us; speedup 1.0000x reference)
//
#include <hip/hip_runtime.h>

constexpr int N_IN  = 128;
constexpr int N_OUT = 32;
constexpr int NR    = 8;    // output ranges == number of XCDs

// ---------------- Kernel 1: h = feat @ W ----------------
__global__ __launch_bounds__(256) void gemm_h(
    const float* __restrict__ feat, const float* __restrict__ W,
    float* __restrict__ h, int n)
{
    __shared__ float Ws[N_IN * N_OUT];  // 16 KB
    for (int i = threadIdx.x; i < (N_IN * N_OUT) / 4; i += 256)
        reinterpret_cast<float4*>(Ws)[i] = reinterpret_cast<const float4*>(W)[i];
    __syncthreads();

    int gid = blockIdx.x * 256 + threadIdx.x;
    int row = gid >> 3;
    if (row >= n) return;
    int cg = (gid & 7) * 4;  // column group start

    const float4* frow = reinterpret_cast<const float4*>(feat + (size_t)row * N_IN);
    float4 acc = make_float4(0.f, 0.f, 0.f, 0.f);
    #pragma unroll
    for (int k4 = 0; k4 < N_IN / 4; ++k4) {
        float4 f = frow[k4];
        int k = k4 * 4;
        float4 w0 = *reinterpret_cast<const float4*>(&Ws[(k + 0) * N_OUT + cg]);
        float4 w1 = *reinterpret_cast<const float4*>(&Ws[(k + 1) * N_OUT + cg]);
        float4 w2 = *reinterpret_cast<const float4*>(&Ws[(k + 2) * N_OUT + cg]);
        float4 w3 = *reinterpret_cast<const float4*>(&Ws[(k + 3) * N_OUT + cg]);
        acc.x += f.x * w0.x + f.y * w1.x + f.z * w2.x + f.w * w3.x;
        acc.y += f.x * w0.y + f.y * w1.y + f.z * w2.y + f.w * w3.y;
        acc.z += f.x * w0.z + f.y * w1.z + f.z * w2.z + f.w * w3.z;
        acc.w += f.x * w0.w + f.y * w1.w + f.z * w2.w + f.w * w3.w;
    }
    *reinterpret_cast<float4*>(h + (size_t)row * N_OUT + cg) = acc;
}

// ---------------- Kernel 2: XCD-range-partitioned scatter-add ----------------
// blockIdx % 8 selects an output node range; round-robin dispatch maps all
// blocks of a given range onto the same XCD -> that XCD's L2 only holds
// 12.8/8 = 1.6 MB of dirty output lines -> atomics stay L2-resident.
// Each block scans an edge chunk (blockIdx / 8) and applies only edges whose
// dst falls in its range. Thread-per-edge; 32 f32 atomics per passing edge.
__global__ __launch_bounds__(256) void scatter_ranged(
    const float* __restrict__ h, const float* __restrict__ edge_w,
    const int* __restrict__ src, const int* __restrict__ dst,
    float* __restrict__ out, int E, int rows_per_range, int nchunks)
{
    int r     = blockIdx.x & (NR - 1);
    int chunk = blockIdx.x >> 3;
    int lo = r * rows_per_range;
    int hi = lo + rows_per_range;

    int epc = (E + nchunks - 1) / nchunks;
    int e0  = chunk * epc;
    int e1  = min(e0 + epc, E);

    for (int e = e0 + (int)threadIdx.x; e < e1; e += 256) {
        int d = dst[e];
        if (d >= lo && d < hi) {
            int s   = src[e];
            float w = edge_w[e];
            const float4* hr = reinterpret_cast<const float4*>(h + (size_t)s * N_OUT);
            float* o = out + (size_t)d * N_OUT;
            float4 hv[8];
            #pragma unroll
            for (int q = 0; q < 8; ++q) hv[q] = hr[q];
            #pragma unroll
            for (int q = 0; q < 8; ++q) {
                atomicAdd(o + 4 * q + 0, hv[q].x * w);
                atomicAdd(o + 4 * q + 1, hv[q].y * w);
                atomicAdd(o + 4 * q + 2, hv[q].z * w);
                atomicAdd(o + 4 * q + 3, hv[q].w * w);
            }
        }
    }
}

// ---------------- Fallback: fused (no workspace) ----------------
__global__ __launch_bounds__(256) void fused_edge(
    const float* __restrict__ feat, const float* __restrict__ W,
    const float* __restrict__ edge_w, const int* __restrict__ src,
    const int* __restrict__ dst, float* __restrict__ out, int E)
{
    __shared__ float Ws[N_IN * N_OUT];
    for (int i = threadIdx.x; i < (N_IN * N_OUT) / 4; i += 256)
        reinterpret_cast<float4*>(Ws)[i] = reinterpret_cast<const float4*>(W)[i];
    __syncthreads();

    int gid = blockIdx.x * 256 + threadIdx.x;
    int e = gid >> 3;
    if (e >= E) return;
    int cg = (gid & 7) * 4;

    int s = src[e];
    int d = dst[e];
    float w = edge_w[e];
    const float4* frow = reinterpret_cast<const float4*>(feat + (size_t)s * N_IN);
    float4 acc = make_float4(0.f, 0.f, 0.f, 0.f);
    #pragma unroll
    for (int k4 = 0; k4 < N_IN / 4; ++k4) {
        float4 f = frow[k4];
        int k = k4 * 4;
        float4 w0 = *reinterpret_cast<const float4*>(&Ws[(k + 0) * N_OUT + cg]);
        float4 w1 = *reinterpret_cast<const float4*>(&Ws[(k + 1) * N_OUT + cg]);
        float4 w2 = *reinterpret_cast<const float4*>(&Ws[(k + 2) * N_OUT + cg]);
        float4 w3 = *reinterpret_cast<const float4*>(&Ws[(k + 3) * N_OUT + cg]);
        acc.x += f.x * w0.x + f.y * w1.x + f.z * w2.x + f.w * w3.x;
        acc.y += f.x * w0.y + f.y * w1.y + f.z * w2.y + f.w * w3.y;
        acc.z += f.x * w0.z + f.y * w1.z + f.z * w2.z + f.w * w3.z;
        acc.w += f.x * w0.w + f.y * w1.w + f.z * w2.w + f.w * w3.w;
    }
    float* o = out + (size_t)d * N_OUT + cg;
    atomicAdd(o + 0, acc.x * w);
    atomicAdd(o + 1, acc.y * w);
    atomicAdd(o + 2, acc.z * w);
    atomicAdd(o + 3, acc.w * w);
}

extern "C" void kernel_launch(void* const* d_in, const int* in_sizes, int n_in,
                              void* d_out, int out_size, void* d_ws, size_t ws_size,
                              hipStream_t stream) {
    const float* feat   = (const float*)d_in[0];
    const float* W      = (const float*)d_in[1];
    const float* edge_w = (const float*)d_in[2];
    const int*   src    = (const int*)d_in[3];
    const int*   dst    = (const int*)d_in[4];
    float* out = (float*)d_out;

    int n = in_sizes[0] / N_IN;   // 100000
    int E = in_sizes[2];          // 1600000

    hipMemsetAsync(d_out, 0, (size_t)out_size * sizeof(float), stream);

    size_t h_bytes = (size_t)n * N_OUT * sizeof(float);
    if (ws_size >= h_bytes) {
        float* h = (float*)d_ws;
        long gthreads = (long)n * 8;
        gemm_h<<<(int)((gthreads + 255) / 256), 256, 0, stream>>>(feat, W, h, n);

        int rows_per_range = (n + NR - 1) / NR;   // 12500
        int nchunks = 256;                         // 8 * 256 = 2048 blocks
        dim3 grid(NR * nchunks);
        scatter_ranged<<<grid, 256, 0, stream>>>(h, edge_w, src, dst, out, E,
                                                 rows_per_range, nchunks);
    } else {
        long sthreads = (long)E * 8;
        fused_edge<<<(int)((sthreads + 255) / 256), 256, 0, stream>>>(feat, W, edge_w, src, dst, out, E);
    }
}

// Round 3
// 260.091 us; speedup vs baseline: 11.1593x; 11.1593x over previous
//
#include <hip/hip_runtime.h>

constexpr int N_IN   = 128;
constexpr int N_OUT  = 32;
constexpr int SCAN_B = 512;

// ---------------- Kernel 1: h = feat @ W ----------------
__global__ __launch_bounds__(256) void gemm_h(
    const float* __restrict__ feat, const float* __restrict__ W,
    float* __restrict__ h, int n)
{
    __shared__ float Ws[N_IN * N_OUT];  // 16 KB
    for (int i = threadIdx.x; i < (N_IN * N_OUT) / 4; i += 256)
        reinterpret_cast<float4*>(Ws)[i] = reinterpret_cast<const float4*>(W)[i];
    __syncthreads();

    int gid = blockIdx.x * 256 + threadIdx.x;
    int row = gid >> 3;
    if (row >= n) return;
    int cg = (gid & 7) * 4;

    const float4* frow = reinterpret_cast<const float4*>(feat + (size_t)row * N_IN);
    float4 acc = make_float4(0.f, 0.f, 0.f, 0.f);
    #pragma unroll
    for (int k4 = 0; k4 < N_IN / 4; ++k4) {
        float4 f = frow[k4];
        int k = k4 * 4;
        float4 w0 = *reinterpret_cast<const float4*>(&Ws[(k + 0) * N_OUT + cg]);
        float4 w1 = *reinterpret_cast<const float4*>(&Ws[(k + 1) * N_OUT + cg]);
        float4 w2 = *reinterpret_cast<const float4*>(&Ws[(k + 2) * N_OUT + cg]);
        float4 w3 = *reinterpret_cast<const float4*>(&Ws[(k + 3) * N_OUT + cg]);
        acc.x += f.x * w0.x + f.y * w1.x + f.z * w2.x + f.w * w3.x;
        acc.y += f.x * w0.y + f.y * w1.y + f.z * w2.y + f.w * w3.y;
        acc.z += f.x * w0.z + f.y * w1.z + f.z * w2.z + f.w * w3.z;
        acc.w += f.x * w0.w + f.y * w1.w + f.z * w2.w + f.w * w3.w;
    }
    *reinterpret_cast<float4*>(h + (size_t)row * N_OUT + cg) = acc;
}

// ---------------- CSR build ----------------
__global__ __launch_bounds__(256) void hist_k(
    const int* __restrict__ dst, int* __restrict__ cnt, int E)
{
    int i = blockIdx.x * 256 + threadIdx.x;
    int stride = gridDim.x * 256;
    for (int e = i; e < E; e += stride) atomicAdd(&cnt[dst[e]], 1);
}

// per-block sums of 512-element chunks
__global__ __launch_bounds__(SCAN_B) void scan1(
    const int* __restrict__ cnt, int* __restrict__ bsum, int n)
{
    __shared__ int s[SCAN_B];
    int g = blockIdx.x * SCAN_B + threadIdx.x;
    s[threadIdx.x] = (g < n) ? cnt[g] : 0;
    __syncthreads();
    for (int off = SCAN_B / 2; off > 0; off >>= 1) {
        if ((int)threadIdx.x < off) s[threadIdx.x] += s[threadIdx.x + off];
        __syncthreads();
    }
    if (threadIdx.x == 0) bsum[blockIdx.x] = s[0];
}

// exclusive scan of block sums (single block; nb <= SCAN_B)
__global__ __launch_bounds__(SCAN_B) void scan2(int* __restrict__ bsum, int nb)
{
    __shared__ int s[SCAN_B];
    int t = threadIdx.x;
    int v = (t < nb) ? bsum[t] : 0;
    s[t] = v;
    __syncthreads();
    for (int off = 1; off < SCAN_B; off <<= 1) {
        int x = (t >= off) ? s[t - off] : 0;
        __syncthreads();
        s[t] += x;
        __syncthreads();
    }
    if (t < nb) bsum[t] = s[t] - v;  // exclusive
}

// intra-block exclusive scan + block offset -> row_start & cursor
__global__ __launch_bounds__(SCAN_B) void scan3(
    const int* __restrict__ cnt, const int* __restrict__ bsum,
    int* __restrict__ row_start, int* __restrict__ cursor, int n)
{
    __shared__ int s[SCAN_B];
    int t = threadIdx.x;
    int g = blockIdx.x * SCAN_B + t;
    int v = (g < n) ? cnt[g] : 0;
    s[t] = v;
    __syncthreads();
    for (int off = 1; off < SCAN_B; off <<= 1) {
        int x = (t >= off) ? s[t - off] : 0;
        __syncthreads();
        s[t] += x;
        __syncthreads();
    }
    int excl = s[t] - v + bsum[blockIdx.x];
    if (g < n) { row_start[g] = excl; cursor[g] = excl; }
}

// bin edges by dst: packed (src, weight) pairs
__global__ __launch_bounds__(256) void scatter_k(
    const int* __restrict__ src, const int* __restrict__ dst,
    const float* __restrict__ w, int* __restrict__ cursor,
    int2* __restrict__ sw, int E)
{
    int i = blockIdx.x * 256 + threadIdx.x;
    int stride = gridDim.x * 256;
    for (int e = i; e < E; e += stride) {
        int d = dst[e];
        int pos = atomicAdd(&cursor[d], 1);
        sw[pos] = make_int2(src[e], __float_as_int(w[e]));
    }
}

// ---------------- Gather: one 8-thread group per node, no atomics ----------
__global__ __launch_bounds__(256) void gather_k(
    const float* __restrict__ h, const int2* __restrict__ sw,
    const int* __restrict__ row_start, float* __restrict__ out, int n, int E)
{
    int gid = blockIdx.x * 256 + threadIdx.x;
    int node = gid >> 3;
    if (node >= n) return;
    int cg = (gid & 7) * 4;

    int lo = row_start[node];
    int hi = (node + 1 < n) ? row_start[node + 1] : E;

    float4 acc = make_float4(0.f, 0.f, 0.f, 0.f);
    for (int j = lo; j < hi; ++j) {
        int2 p = sw[j];
        float wv = __int_as_float(p.y);
        float4 hv = *reinterpret_cast<const float4*>(h + (size_t)p.x * N_OUT + cg);
        acc.x += hv.x * wv;
        acc.y += hv.y * wv;
        acc.z += hv.z * wv;
        acc.w += hv.w * wv;
    }
    *reinterpret_cast<float4*>(out + (size_t)node * N_OUT + cg) = acc;
}

// ---------------- Fallback kernels (small workspace) ----------------
__global__ __launch_bounds__(256) void scatter_add(
    const float* __restrict__ h, const float* __restrict__ edge_w,
    const int* __restrict__ src, const int* __restrict__ dst,
    float* __restrict__ out, int E)
{
    int gid = blockIdx.x * 256 + threadIdx.x;
    int e = gid >> 3;
    if (e >= E) return;
    int cg = (gid & 7) * 4;
    int s = src[e];
    int d = dst[e];
    float w = edge_w[e];
    float4 hv = *reinterpret_cast<const float4*>(h + (size_t)s * N_OUT + cg);
    float* o = out + (size_t)d * N_OUT + cg;
    atomicAdd(o + 0, hv.x * w);
    atomicAdd(o + 1, hv.y * w);
    atomicAdd(o + 2, hv.z * w);
    atomicAdd(o + 3, hv.w * w);
}

__global__ __launch_bounds__(256) void fused_edge(
    const float* __restrict__ feat, const float* __restrict__ W,
    const float* __restrict__ edge_w, const int* __restrict__ src,
    const int* __restrict__ dst, float* __restrict__ out, int E)
{
    __shared__ float Ws[N_IN * N_OUT];
    for (int i = threadIdx.x; i < (N_IN * N_OUT) / 4; i += 256)
        reinterpret_cast<float4*>(Ws)[i] = reinterpret_cast<const float4*>(W)[i];
    __syncthreads();
    int gid = blockIdx.x * 256 + threadIdx.x;
    int e = gid >> 3;
    if (e >= E) return;
    int cg = (gid & 7) * 4;
    int s = src[e];
    int d = dst[e];
    float w = edge_w[e];
    const float4* frow = reinterpret_cast<const float4*>(feat + (size_t)s * N_IN);
    float4 acc = make_float4(0.f, 0.f, 0.f, 0.f);
    #pragma unroll
    for (int k4 = 0; k4 < N_IN / 4; ++k4) {
        float4 f = frow[k4];
        int k = k4 * 4;
        float4 w0 = *reinterpret_cast<const float4*>(&Ws[(k + 0) * N_OUT + cg]);
        float4 w1 = *reinterpret_cast<const float4*>(&Ws[(k + 1) * N_OUT + cg]);
        float4 w2 = *reinterpret_cast<const float4*>(&Ws[(k + 2) * N_OUT + cg]);
        float4 w3 = *reinterpret_cast<const float4*>(&Ws[(k + 3) * N_OUT + cg]);
        acc.x += f.x * w0.x + f.y * w1.x + f.z * w2.x + f.w * w3.x;
        acc.y += f.x * w0.y + f.y * w1.y + f.z * w2.y + f.w * w3.y;
        acc.z += f.x * w0.z + f.y * w1.z + f.z * w2.z + f.w * w3.z;
        acc.w += f.x * w0.w + f.y * w1.w + f.z * w2.w + f.w * w3.w;
    }
    float* o = out + (size_t)d * N_OUT + cg;
    atomicAdd(o + 0, acc.x * w);
    atomicAdd(o + 1, acc.y * w);
    atomicAdd(o + 2, acc.z * w);
    atomicAdd(o + 3, acc.w * w);
}

extern "C" void kernel_launch(void* const* d_in, const int* in_sizes, int n_in,
                              void* d_out, int out_size, void* d_ws, size_t ws_size,
                              hipStream_t stream) {
    const float* feat   = (const float*)d_in[0];
    const float* W      = (const float*)d_in[1];
    const float* edge_w = (const float*)d_in[2];
    const int*   src    = (const int*)d_in[3];
    const int*   dst    = (const int*)d_in[4];
    float* out = (float*)d_out;

    int n = in_sizes[0] / N_IN;   // 100000
    int E = in_sizes[2];          // 1600000

    // workspace layout (bytes)
    size_t off_h      = 0;
    size_t off_rs     = off_h + (size_t)n * N_OUT * sizeof(float);   // row_start
    size_t off_cur    = off_rs + (size_t)n * sizeof(int);            // cursor / cnt
    size_t off_bsum   = off_cur + (size_t)n * sizeof(int);           // block sums
    size_t off_sw     = off_bsum + (size_t)SCAN_B * sizeof(int);
    size_t need       = off_sw + (size_t)E * sizeof(int2);

    char* ws = (char*)d_ws;

    if (ws_size >= need) {
        float* h        = (float*)(ws + off_h);
        int*   rowstart = (int*)(ws + off_rs);
        int*   cursor   = (int*)(ws + off_cur);
        int*   bsum     = (int*)(ws + off_bsum);
        int2*  sw       = (int2*)(ws + off_sw);

        long gthreads = (long)n * 8;
        gemm_h<<<(int)((gthreads + 255) / 256), 256, 0, stream>>>(feat, W, h, n);

        hipMemsetAsync(cursor, 0, (size_t)n * sizeof(int), stream);  // cnt = 0
        hist_k<<<2048, 256, 0, stream>>>(dst, cursor, E);

        int nb = (n + SCAN_B - 1) / SCAN_B;  // 196
        scan1<<<nb, SCAN_B, 0, stream>>>(cursor, bsum, n);
        scan2<<<1, SCAN_B, 0, stream>>>(bsum, nb);
        scan3<<<nb, SCAN_B, 0, stream>>>(cursor, bsum, rowstart, cursor, n);

        scatter_k<<<2048, 256, 0, stream>>>(src, dst, edge_w, cursor, sw, E);

        gather_k<<<(int)((gthreads + 255) / 256), 256, 0, stream>>>(h, sw, rowstart, out, n, E);
    } else {
        hipMemsetAsync(d_out, 0, (size_t)out_size * sizeof(float), stream);
        size_t h_bytes = (size_t)n * N_OUT * sizeof(float);
        if (ws_size >= h_bytes) {
            float* h = (float*)d_ws;
            long gthreads = (long)n * 8;
            gemm_h<<<(int)((gthreads + 255) / 256), 256, 0, stream>>>(feat, W, h, n);
            long sthreads = (long)E * 8;
            scatter_add<<<(int)((sthreads + 255) / 256), 256, 0, stream>>>(h, edge_w, src, dst, out, E);
        } else {
            long sthreads = (long)E * 8;
            fused_edge<<<(int)((sthreads + 255) / 256), 256, 0, stream>>>(feat, W, edge_w, src, dst, out, E);
        }
    }
}